// Round 10
// baseline (557.840 us; speedup 1.0000x reference)
//
#include <hip/hip_runtime.h>
#include <hip/hip_bf16.h>
#include <math.h>

#define N_NODES 100000
#define N_EDGES 1600000

// bucketed CSR build params
constexpr int BSHIFT = 9, BMASK = 511;           // 512 nodes per bucket
constexpr int NBUCKET = (N_NODES + 511) / 512;   // 196
constexpr int BCAP = 16384;                      // entries per bucket (mean 8192)
constexpr int CAPB = 12288;                      // LDS col staging entries
constexpr int EPT = 16, BIN_T = 256, BIN_CHUNK = BIN_T * EPT;  // 4096 edges/block

typedef __attribute__((ext_vector_type(8))) short bf16x8;
typedef __attribute__((ext_vector_type(4))) float f32x4;

__device__ __forceinline__ unsigned short f2bf(float f) {
    unsigned int u = __float_as_uint(f);
    unsigned int r = (u + 0x7fff + ((u >> 16) & 1)) >> 16;  // RNE, finite inputs
    return (unsigned short)r;
}

// ---------------- CSR build (bucketed) ----------------

__global__ __launch_bounds__(BIN_T) void bin_kernel(const int* __restrict__ src,
                                                    const int* __restrict__ dst,
                                                    int* __restrict__ bcnt,
                                                    unsigned int* __restrict__ bstore, int E) {
    __shared__ int cnt[NBUCKET];
    __shared__ int base[NBUCKET];
    int t = threadIdx.x;
    for (int i = t; i < NBUCKET; i += BIN_T) cnt[i] = 0;
    __syncthreads();
    int e0 = blockIdx.x * BIN_CHUNK;
    int ssrc[EPT], sdst[EPT];
#pragma unroll
    for (int k = 0; k < EPT; ++k) {
        int e = e0 + t + k * BIN_T;
        if (e < E) {
            ssrc[k] = src[e];
            sdst[k] = dst[e];
            atomicAdd(&cnt[sdst[k] >> BSHIFT], 1);
        } else {
            sdst[k] = -1;
        }
    }
    __syncthreads();
    for (int i = t; i < NBUCKET; i += BIN_T) {
        base[i] = atomicAdd(&bcnt[i], cnt[i]);
        cnt[i] = 0;
    }
    __syncthreads();
#pragma unroll
    for (int k = 0; k < EPT; ++k) {
        if (sdst[k] >= 0) {
            int b = sdst[k] >> BSHIFT;
            int off = base[b] + atomicAdd(&cnt[b], 1);
            if (off < BCAP)
                bstore[(size_t)b * BCAP + off] =
                    ((unsigned)ssrc[k] << BSHIFT) | (unsigned)(sdst[k] & BMASK);
        }
    }
}

// Per bucket: scan bucket counts (redundant per-block, 196 vals, cheap) -> gbase;
// LDS histogram -> in-LDS scan -> write rp; stage col in LDS -> coalesced write.
__global__ __launch_bounds__(256) void build_col_v3(const int* __restrict__ bcnt,
                                                    const unsigned int* __restrict__ bstore,
                                                    int* __restrict__ rp, int* __restrict__ col,
                                                    int N) {
    __shared__ int sc[256];
    __shared__ int sA[512], sB[512];
    __shared__ int lofs[513];
    __shared__ int colStage[CAPB];
    int b = blockIdx.x, t = threadIdx.x;
    // scan of all bucket counts (inclusive) in sc
    int v = (t < NBUCKET) ? min(bcnt[t], BCAP) : 0;
    sc[t] = v;
    __syncthreads();
    for (int off = 1; off < 256; off <<= 1) {
        int x = (t >= off) ? sc[t - off] : 0;
        __syncthreads();
        sc[t] += x;
        __syncthreads();
    }
    int gbase = (b == 0) ? 0 : sc[b - 1];

    int nodeBase = b << BSHIFT;
    int nNodes = min(512, N - nodeBase);
    for (int i = t; i < 512; i += 256) sA[i] = 0;
    __syncthreads();
    int cnt = min(bcnt[b], BCAP);
    size_t sbase = (size_t)b * BCAP;
    for (int i = t; i < cnt; i += 256) atomicAdd(&sA[bstore[sbase + i] & BMASK], 1);
    __syncthreads();
    // ping-pong inclusive scan of 512 with 256 threads
    int* srcp = sA; int* dstp = sB;
    for (int off = 1; off < 512; off <<= 1) {
        for (int i = t; i < 512; i += 256) dstp[i] = srcp[i] + ((i >= off) ? srcp[i - off] : 0);
        __syncthreads();
        int* tmp = srcp; srcp = dstp; dstp = tmp;
    }
    for (int i = t; i < 512; i += 256) lofs[i + 1] = srcp[i];
    if (t == 0) lofs[0] = 0;
    // reuse dstp as fill counters
    for (int i = t; i < 512; i += 256) dstp[i] = 0;
    __syncthreads();
    for (int i = t; i < nNodes; i += 256) rp[nodeBase + i] = gbase + lofs[i];
    if (b == NBUCKET - 1 && t == 0) rp[N] = gbase + lofs[nNodes];
    for (int i = t; i < cnt; i += 256) {
        unsigned e = bstore[sbase + i];
        int dl = e & BMASK;
        int sv = (int)(e >> BSHIFT);
        int pos = lofs[dl] + atomicAdd(&dstp[dl], 1);
        if (pos < CAPB) colStage[pos] = sv;
        else col[gbase + pos] = sv;   // overflow fallback
    }
    __syncthreads();
    int lim = min(cnt, CAPB);
    for (int i = t; i < lim; i += 256) col[gbase + i] = colStage[i];
}

// ---------------- merged W transpose + bf16 cast ----------------
// WtX[c][k] = bf16(W[k][c]) for c < C; rows C..C+3 filled by fuse_dots.
__global__ __launch_bounds__(256) void transpose_all_w(
    const float* __restrict__ W0, const float* __restrict__ W1,
    const float* __restrict__ W2, const float* __restrict__ W3,
    unsigned int* __restrict__ Wt0, unsigned int* __restrict__ Wt1,
    unsigned int* __restrict__ Wt2, unsigned int* __restrict__ Wt3) {
    int idx = blockIdx.x * 256 + threadIdx.x;
    const float* W; unsigned int* Wt; int C, base;
    if (idx < 8192)       { W = W0; Wt = Wt0; C = 128; base = 0; }
    else if (idx < 16384) { W = W1; Wt = Wt1; C = 128; base = 8192; }
    else if (idx < 24576) { W = W2; Wt = Wt2; C = 128; base = 16384; }
    else if (idx < 28672) { W = W3; Wt = Wt3; C = 64;  base = 24576; }
    else return;
    int l = idx - base;
    int c = l >> 6, kk = l & 63;
    float w0 = W[(2 * kk) * C + c];
    float w1 = W[(2 * kk + 1) * C + c];
    Wt[c * 64 + kk] = (unsigned)f2bf(w0) | ((unsigned)f2bf(w1) << 16);
}

// Fused dot columns: WtX rows C+v (v=0: ws_h0, 1: ws_h1, 2: wd_h0, 3: wd_h1),
// ws[k] = sum_d W[k][h*dout+d]*a[h*dout+d]; pad rows C+4..NTILES*16-1 zeroed.
__global__ __launch_bounds__(512) void fuse_dots(
    const float* __restrict__ W0, const float* __restrict__ W1,
    const float* __restrict__ W2, const float* __restrict__ W3,
    const float* __restrict__ as0, const float* __restrict__ ad0,
    const float* __restrict__ as1, const float* __restrict__ ad1,
    const float* __restrict__ as2, const float* __restrict__ ad2,
    const float* __restrict__ as3, const float* __restrict__ ad3,
    unsigned short* __restrict__ Wt0, unsigned short* __restrict__ Wt1,
    unsigned short* __restrict__ Wt2, unsigned short* __restrict__ Wt3) {
    int l = blockIdx.x;   // layer 0..3
    int t = threadIdx.x;  // 0..511
    const float* W  = (l == 0) ? W0 : (l == 1) ? W1 : (l == 2) ? W2 : W3;
    const float* as = (l == 0) ? as0 : (l == 1) ? as1 : (l == 2) ? as2 : as3;
    const float* ad = (l == 0) ? ad0 : (l == 1) ? ad1 : (l == 2) ? ad2 : ad3;
    unsigned short* Wt = (l == 0) ? Wt0 : (l == 1) ? Wt1 : (l == 2) ? Wt2 : Wt3;
    int C = (l < 3) ? 128 : 64;
    int dout = C / 2;
    int k = t & 127, v = t >> 7;          // v: 0=s/h0 1=s/h1 2=d/h0 3=d/h1
    int head = v & 1;
    const float* a = (v >> 1) ? ad : as;
    float s = 0.f;
    for (int d = 0; d < dout; ++d)
        s += W[k * C + head * dout + d] * a[head * dout + d];
    Wt[(C + v) * 128 + k] = f2bf(s);
    // zero the pad rows (C+4 .. NTILES*16-1); 12 rows x 128 for all layers
    int padBase = (C + 4) * 128;
    for (int i = t; i < 12 * 128; i += 512) Wt[padBase + i] = 0;
}

// ---------------- per-layer GEMM via MFMA (dots fused as extra B-tile) ----------------
// 1 wave / block, 16 nodes. F32IN: stage fp32 h via LDS; else direct bf16 loads.
// D tile layout (m89): col = lane&15, row = (lane>>4)*4 + reg.
// Extra tile NT: cols C..C+3 = (asrc_h0, asrc_h1, adst_h0, adst_h1).

template<int HD, bool F32IN>
__global__ __launch_bounds__(64) void gemm_alpha_mfma(
    const void* __restrict__ hsrc, const unsigned short* __restrict__ Wt,
    __hip_bfloat16* __restrict__ xl, float* __restrict__ asrc, float* __restrict__ adst) {
    constexpr int NT = HD / 16;       // output col tiles (8 or 4); tile NT = dots
    constexpr int GR = HD / 4;        // uint2 groups per out row
    int node0 = blockIdx.x * 16;
    int t = threadIdx.x;
    int lan = t & 15, grp = t >> 4;

    __shared__ float ob[16][HD + 4];  // D staging for transpose

    bf16x8 af[4];
    if constexpr (F32IN) {
        __shared__ unsigned short hb[16][136];
        const float4* h4 = (const float4*)hsrc;
#pragma unroll
        for (int it = 0; it < 8; ++it) {
            int idx = it * 64 + t;
            int nn = idx >> 5, kk = idx & 31;
            float4 v = h4[(size_t)(node0 + nn) * 32 + kk];
            ushort4 u;
            u.x = f2bf(v.x); u.y = f2bf(v.y); u.z = f2bf(v.z); u.w = f2bf(v.w);
            *(ushort4*)&hb[nn][kk * 4] = u;
        }
        __syncthreads();
#pragma unroll
        for (int ks = 0; ks < 4; ++ks)
            af[ks] = *(const bf16x8*)&hb[lan][ks * 32 + grp * 8];
    } else {
        const unsigned short* hbf = (const unsigned short*)hsrc;
#pragma unroll
        for (int ks = 0; ks < 4; ++ks)
            af[ks] = *(const bf16x8*)(hbf + (size_t)(node0 + lan) * 128 + ks * 32 + grp * 8);
    }

    f32x4 acc[NT + 1];
#pragma unroll
    for (int i = 0; i <= NT; ++i) acc[i] = (f32x4){0.f, 0.f, 0.f, 0.f};

#pragma unroll
    for (int ks = 0; ks < 4; ++ks) {
        bf16x8 bfr[NT + 1];
#pragma unroll
        for (int nt = 0; nt <= NT; ++nt)
            bfr[nt] = *(const bf16x8*)(Wt + (size_t)(nt * 16 + lan) * 128 + ks * 32 + grp * 8);
#pragma unroll
        for (int nt = 0; nt <= NT; ++nt)
            acc[nt] = __builtin_amdgcn_mfma_f32_16x16x32_bf16(af[ks], bfr[nt], acc[nt], 0, 0, 0);
    }

    // dots live in acc[NT], col=lan: 0=asrc_h0 1=asrc_h1 2=adst_h0 3=adst_h1
    if (lan < 4) {
        float* dst = (lan < 2) ? asrc : adst;
        int hh = lan & 1;
#pragma unroll
        for (int j = 0; j < 4; ++j) {
            int node = node0 + grp * 4 + j;
            dst[node * 2 + hh] = acc[NT][j];
        }
    }

    // transpose D through LDS, emit xl bf16 packed
#pragma unroll
    for (int nt = 0; nt < NT; ++nt)
#pragma unroll
        for (int j = 0; j < 4; ++j)
            ob[grp * 4 + j][nt * 16 + lan] = acc[nt][j];
    __syncthreads();
#pragma unroll
    for (int it = 0; it < 16 * GR / 64; ++it) {
        int idx = it * 64 + t;
        int nn = idx / GR, g = idx % GR;
        float4 v = *(const float4*)&ob[nn][g * 4];
        uint2 u;
        u.x = (unsigned)f2bf(v.x) | ((unsigned)f2bf(v.y) << 16);
        u.y = (unsigned)f2bf(v.z) | ((unsigned)f2bf(v.w) << 16);
        ((uint2*)xl)[(size_t)(node0 + nn) * GR + g] = u;
    }
}

// ---------------- aggregation v5: bf16 gather, bf16 packed output ----------------

__global__ void aggregate_relu_v5(const __hip_bfloat162* __restrict__ xl2,
                                  const float2* __restrict__ a_src, const float2* __restrict__ a_dst,
                                  const int* __restrict__ rp, const int* __restrict__ col,
                                  const float* __restrict__ bias, unsigned int* __restrict__ out) {
    int node = blockIdx.x;
    int t = threadIdx.x;           // 0..63
    int head = t >> 5;
    int beg = rp[node], deg = rp[node + 1] - beg;
    float2 adn = a_dst[node];

    __shared__ int   snS[64];
    __shared__ float pS[2][64];

    float s0 = 0.f, s1 = 0.f;
    float ax0 = 0.f, ay0 = 0.f, ax1 = 0.f, ay1 = 0.f;
    float ax2 = 0.f, ay2 = 0.f, ax3 = 0.f, ay3 = 0.f;

    if (deg <= 64) {
        float e0 = -INFINITY, e1 = -INFINITY;
        if (t < deg) {
            int sn = col[beg + t];
            snS[t] = sn;
            float2 a = a_src[sn];
            e0 = a.x + adn.x; e0 = (e0 >= 0.f) ? e0 : 0.2f * e0;
            e1 = a.y + adn.y; e1 = (e1 >= 0.f) ? e1 : 0.2f * e1;
        }
        float m0 = e0, m1 = e1;
#pragma unroll
        for (int off = 32; off >= 1; off >>= 1) {
            m0 = fmaxf(m0, __shfl_xor(m0, off, 64));
            m1 = fmaxf(m1, __shfl_xor(m1, off, 64));
        }
        if (t < deg) {
            float p0 = __expf(e0 - m0), p1 = __expf(e1 - m1);
            pS[0][t] = p0; pS[1][t] = p1;
            s0 = p0; s1 = p1;
        }
        __syncthreads();
        int j = 0;
        for (; j + 8 <= deg; j += 8) {
            int sa = snS[j+0], sb = snS[j+1], sc = snS[j+2], sd = snS[j+3];
            int se = snS[j+4], sf = snS[j+5], sg = snS[j+6], sh = snS[j+7];
            float pa = pS[head][j+0], pb = pS[head][j+1], pc = pS[head][j+2], pd = pS[head][j+3];
            float pe = pS[head][j+4], pf = pS[head][j+5], pg = pS[head][j+6], ph = pS[head][j+7];
            __hip_bfloat162 va = xl2[(size_t)sa * 64 + t];
            __hip_bfloat162 vb = xl2[(size_t)sb * 64 + t];
            __hip_bfloat162 vc = xl2[(size_t)sc * 64 + t];
            __hip_bfloat162 vd = xl2[(size_t)sd * 64 + t];
            __hip_bfloat162 ve = xl2[(size_t)se * 64 + t];
            __hip_bfloat162 vf = xl2[(size_t)sf * 64 + t];
            __hip_bfloat162 vg = xl2[(size_t)sg * 64 + t];
            __hip_bfloat162 vh = xl2[(size_t)sh * 64 + t];
            ax0 = fmaf(pa, __bfloat162float(va.x), ax0); ay0 = fmaf(pa, __bfloat162float(va.y), ay0);
            ax1 = fmaf(pb, __bfloat162float(vb.x), ax1); ay1 = fmaf(pb, __bfloat162float(vb.y), ay1);
            ax2 = fmaf(pc, __bfloat162float(vc.x), ax2); ay2 = fmaf(pc, __bfloat162float(vc.y), ay2);
            ax3 = fmaf(pd, __bfloat162float(vd.x), ax3); ay3 = fmaf(pd, __bfloat162float(vd.y), ay3);
            ax0 = fmaf(pe, __bfloat162float(ve.x), ax0); ay0 = fmaf(pe, __bfloat162float(ve.y), ay0);
            ax1 = fmaf(pf, __bfloat162float(vf.x), ax1); ay1 = fmaf(pf, __bfloat162float(vf.y), ay1);
            ax2 = fmaf(pg, __bfloat162float(vg.x), ax2); ay2 = fmaf(pg, __bfloat162float(vg.y), ay2);
            ax3 = fmaf(ph, __bfloat162float(vh.x), ax3); ay3 = fmaf(ph, __bfloat162float(vh.y), ay3);
        }
        for (; j < deg; ++j) {
            int sn = snS[j];
            float p = pS[head][j];
            __hip_bfloat162 v = xl2[(size_t)sn * 64 + t];
            ax0 = fmaf(p, __bfloat162float(v.x), ax0);
            ay0 = fmaf(p, __bfloat162float(v.y), ay0);
        }
    } else {
        float m0 = -INFINITY, m1 = -INFINITY;
        for (int j = t; j < deg; j += 64) {
            float2 a = a_src[col[beg + j]];
            float e0 = a.x + adn.x; e0 = (e0 >= 0.f) ? e0 : 0.2f * e0;
            float e1 = a.y + adn.y; e1 = (e1 >= 0.f) ? e1 : 0.2f * e1;
            m0 = fmaxf(m0, e0); m1 = fmaxf(m1, e1);
        }
#pragma unroll
        for (int off = 32; off >= 1; off >>= 1) {
            m0 = fmaxf(m0, __shfl_xor(m0, off, 64));
            m1 = fmaxf(m1, __shfl_xor(m1, off, 64));
        }
        for (int c0 = 0; c0 < deg; c0 += 64) {
            int csz = min(64, deg - c0);
            if (t < csz) {
                int sn = col[beg + c0 + t];
                float2 a = a_src[sn];
                float e0 = a.x + adn.x; e0 = (e0 >= 0.f) ? e0 : 0.2f * e0;
                float e1 = a.y + adn.y; e1 = (e1 >= 0.f) ? e1 : 0.2f * e1;
                float p0 = __expf(e0 - m0), p1 = __expf(e1 - m1);
                snS[t] = sn; pS[0][t] = p0; pS[1][t] = p1;
                s0 += p0; s1 += p1;
            }
            __syncthreads();
            for (int j = 0; j < csz; ++j) {
                int sn = snS[j];
                float p = pS[head][j];
                __hip_bfloat162 v = xl2[(size_t)sn * 64 + t];
                ax0 = fmaf(p, __bfloat162float(v.x), ax0);
                ay0 = fmaf(p, __bfloat162float(v.y), ay0);
            }
            __syncthreads();
        }
    }
#pragma unroll
    for (int off = 32; off >= 1; off >>= 1) {
        s0 += __shfl_xor(s0, off, 64);
        s1 += __shfl_xor(s1, off, 64);
    }
    float s = head ? s1 : s0;
    float inv = 1.0f / (s + 1e-16f);
    float2 b2 = ((const float2*)bias)[t];
    float ox = fmaxf(fmaf(ax0 + ax1 + ax2 + ax3, inv, b2.x), 0.f);
    float oy = fmaxf(fmaf(ay0 + ay1 + ay2 + ay3, inv, b2.y), 0.f);
    out[(size_t)node * 64 + t] = (unsigned)f2bf(ox) | ((unsigned)f2bf(oy) << 16);
}

__global__ void aggregate_final_v4(const __hip_bfloat16* __restrict__ xl,
                                   const float2* __restrict__ a_src, const float2* __restrict__ a_dst,
                                   const int* __restrict__ rp, const int* __restrict__ col,
                                   const float* __restrict__ bias, float* __restrict__ out) {
    int node = blockIdx.x;
    int t = threadIdx.x;  // 0..63
    int head = t >> 5;
    int beg = rp[node], deg = rp[node + 1] - beg;
    float2 adn = a_dst[node];

    __shared__ int   snS[64];
    __shared__ float pS[2][64];

    float s0 = 0.f, s1 = 0.f;
    float a0 = 0.f, a1 = 0.f, a2 = 0.f, a3 = 0.f;

    if (deg <= 64) {
        float e0 = -INFINITY, e1 = -INFINITY;
        if (t < deg) {
            int sn = col[beg + t];
            snS[t] = sn;
            float2 a = a_src[sn];
            e0 = a.x + adn.x; e0 = (e0 >= 0.f) ? e0 : 0.2f * e0;
            e1 = a.y + adn.y; e1 = (e1 >= 0.f) ? e1 : 0.2f * e1;
        }
        float m0 = e0, m1 = e1;
#pragma unroll
        for (int off = 32; off >= 1; off >>= 1) {
            m0 = fmaxf(m0, __shfl_xor(m0, off, 64));
            m1 = fmaxf(m1, __shfl_xor(m1, off, 64));
        }
        if (t < deg) {
            float p0 = __expf(e0 - m0), p1 = __expf(e1 - m1);
            pS[0][t] = p0; pS[1][t] = p1;
            s0 = p0; s1 = p1;
        }
        __syncthreads();
        int j = 0;
        for (; j + 8 <= deg; j += 8) {
            int sa = snS[j+0], sb = snS[j+1], sc = snS[j+2], sd = snS[j+3];
            int se = snS[j+4], sf = snS[j+5], sg = snS[j+6], sh = snS[j+7];
            float pa = pS[head][j+0], pb = pS[head][j+1], pc = pS[head][j+2], pd = pS[head][j+3];
            float pe = pS[head][j+4], pf = pS[head][j+5], pg = pS[head][j+6], ph = pS[head][j+7];
            float va = __bfloat162float(xl[(size_t)sa * 64 + t]);
            float vb = __bfloat162float(xl[(size_t)sb * 64 + t]);
            float vc = __bfloat162float(xl[(size_t)sc * 64 + t]);
            float vd = __bfloat162float(xl[(size_t)sd * 64 + t]);
            float ve = __bfloat162float(xl[(size_t)se * 64 + t]);
            float vf = __bfloat162float(xl[(size_t)sf * 64 + t]);
            float vg = __bfloat162float(xl[(size_t)sg * 64 + t]);
            float vh = __bfloat162float(xl[(size_t)sh * 64 + t]);
            a0 = fmaf(pa, va, a0); a1 = fmaf(pb, vb, a1);
            a2 = fmaf(pc, vc, a2); a3 = fmaf(pd, vd, a3);
            a0 = fmaf(pe, ve, a0); a1 = fmaf(pf, vf, a1);
            a2 = fmaf(pg, vg, a2); a3 = fmaf(ph, vh, a3);
        }
        for (; j < deg; ++j) {
            a0 = fmaf(pS[head][j], __bfloat162float(xl[(size_t)snS[j] * 64 + t]), a0);
        }
    } else {
        float m0 = -INFINITY, m1 = -INFINITY;
        for (int j = t; j < deg; j += 64) {
            float2 a = a_src[col[beg + j]];
            float e0 = a.x + adn.x; e0 = (e0 >= 0.f) ? e0 : 0.2f * e0;
            float e1 = a.y + adn.y; e1 = (e1 >= 0.f) ? e1 : 0.2f * e1;
            m0 = fmaxf(m0, e0); m1 = fmaxf(m1, e1);
        }
#pragma unroll
        for (int off = 32; off >= 1; off >>= 1) {
            m0 = fmaxf(m0, __shfl_xor(m0, off, 64));
            m1 = fmaxf(m1, __shfl_xor(m1, off, 64));
        }
        for (int c0 = 0; c0 < deg; c0 += 64) {
            int csz = min(64, deg - c0);
            if (t < csz) {
                int sn = col[beg + c0 + t];
                float2 a = a_src[sn];
                float e0 = a.x + adn.x; e0 = (e0 >= 0.f) ? e0 : 0.2f * e0;
                float e1 = a.y + adn.y; e1 = (e1 >= 0.f) ? e1 : 0.2f * e1;
                float p0 = __expf(e0 - m0), p1 = __expf(e1 - m1);
                snS[t] = sn; pS[0][t] = p0; pS[1][t] = p1;
                s0 += p0; s1 += p1;
            }
            __syncthreads();
            for (int j = 0; j < csz; ++j) {
                a0 = fmaf(pS[head][j], __bfloat162float(xl[(size_t)snS[j] * 64 + t]), a0);
            }
            __syncthreads();
        }
    }
#pragma unroll
    for (int off = 32; off >= 1; off >>= 1) {
        s0 += __shfl_xor(s0, off, 64);
        s1 += __shfl_xor(s1, off, 64);
    }
    float s = head ? s1 : s0;
    float o = (a0 + a1 + a2 + a3) / (s + 1e-16f);
    float other = __shfl_down(o, 32, 64);
    if (t < 32) {
        float v = 0.5f * (o + other) + bias[t];
        float mx = v;
#pragma unroll
        for (int off = 16; off >= 1; off >>= 1) mx = fmaxf(mx, __shfl_xor(mx, off, 32));
        float ex = __expf(v - mx);
        float sm = ex;
#pragma unroll
        for (int off = 16; off >= 1; off >>= 1) sm += __shfl_xor(sm, off, 32);
        out[(size_t)node * 32 + t] = v - mx - logf(sm);
    }
}

// ---------------- launch ----------------

extern "C" void kernel_launch(void* const* d_in, const int* in_sizes, int n_in,
                              void* d_out, int out_size, void* d_ws, size_t ws_size,
                              hipStream_t stream) {
    const int N = N_NODES, E = N_EDGES;

    const float* x  = (const float*)d_in[0];
    const int*  ei  = (const int*)d_in[1];
    const float* W0 = (const float*)d_in[2];
    const float* as0 = (const float*)d_in[3];
    const float* ad0 = (const float*)d_in[4];
    const float* b0 = (const float*)d_in[5];
    const float* W1 = (const float*)d_in[6];
    const float* as1 = (const float*)d_in[7];
    const float* ad1 = (const float*)d_in[8];
    const float* b1 = (const float*)d_in[9];
    const float* W2 = (const float*)d_in[10];
    const float* as2 = (const float*)d_in[11];
    const float* ad2 = (const float*)d_in[12];
    const float* b2 = (const float*)d_in[13];
    const float* W3 = (const float*)d_in[14];
    const float* as3 = (const float*)d_in[15];
    const float* ad3 = (const float*)d_in[16];
    const float* b3 = (const float*)d_in[17];
    float* out = (float*)d_out;

    const int* srcv = ei;       // edge_index[0]
    const int* dstv = ei + E;   // edge_index[1]

    char* p = (char*)d_ws;
    auto carve = [&](size_t bytes) -> void* {
        void* r = (void*)p;
        p += (bytes + 255) & ~(size_t)255;
        return r;
    };
    int* rp       = (int*)carve((size_t)(N + 1) * 4);
    int* col      = (int*)carve((size_t)E * 4);
    int* bcnt     = (int*)carve((size_t)NBUCKET * 4);
    unsigned int* bstore = (unsigned int*)carve((size_t)NBUCKET * BCAP * 4);
    __hip_bfloat16* bufX = (__hip_bfloat16*)carve((size_t)N * 128 * 2);  // xl, bf16
    __hip_bfloat16* bufH = (__hip_bfloat16*)carve((size_t)N * 128 * 2);  // h, bf16
    float* asrc   = (float*)carve((size_t)N * 2 * 4);
    float* adst   = (float*)carve((size_t)N * 2 * 4);
    unsigned short* Wt0 = (unsigned short*)carve((size_t)144 * 128 * 2);  // 9 tiles
    unsigned short* Wt1 = (unsigned short*)carve((size_t)144 * 128 * 2);
    unsigned short* Wt2 = (unsigned short*)carve((size_t)144 * 128 * 2);
    unsigned short* Wt3 = (unsigned short*)carve((size_t)80 * 128 * 2);   // 5 tiles

    hipMemsetAsync(bcnt, 0, (size_t)NBUCKET * 4, stream);

    // bf16 transposed weights + fused dot columns
    transpose_all_w<<<112, 256, 0, stream>>>(W0, W1, W2, W3,
                                             (unsigned int*)Wt0, (unsigned int*)Wt1,
                                             (unsigned int*)Wt2, (unsigned int*)Wt3);
    fuse_dots<<<4, 512, 0, stream>>>(W0, W1, W2, W3,
                                     as0, ad0, as1, ad1, as2, ad2, as3, ad3,
                                     Wt0, Wt1, Wt2, Wt3);

    // bucketed CSR build
    bin_kernel<<<(E + BIN_CHUNK - 1) / BIN_CHUNK, BIN_T, 0, stream>>>(srcv, dstv, bcnt, bstore, E);
    build_col_v3<<<NBUCKET, 256, 0, stream>>>(bcnt, bstore, rp, col, N);

    const __hip_bfloat162* bufX2 = (const __hip_bfloat162*)bufX;
    const float2* asrc2 = (const float2*)asrc;
    const float2* adst2 = (const float2*)adst;

    // layer 0 (fp32 input)
    gemm_alpha_mfma<128, true><<<N / 16, 64, 0, stream>>>(x, Wt0, bufX, asrc, adst);
    aggregate_relu_v5<<<N, 64, 0, stream>>>(bufX2, asrc2, adst2, rp, col, b0, (unsigned int*)bufH);
    // layer 1 (bf16 input)
    gemm_alpha_mfma<128, false><<<N / 16, 64, 0, stream>>>(bufH, Wt1, bufX, asrc, adst);
    aggregate_relu_v5<<<N, 64, 0, stream>>>(bufX2, asrc2, adst2, rp, col, b1, (unsigned int*)bufH);
    // layer 2
    gemm_alpha_mfma<128, false><<<N / 16, 64, 0, stream>>>(bufH, Wt2, bufX, asrc, adst);
    aggregate_relu_v5<<<N, 64, 0, stream>>>(bufX2, asrc2, adst2, rp, col, b2, (unsigned int*)bufH);
    // layer 3
    gemm_alpha_mfma<64, false><<<N / 16, 64, 0, stream>>>(bufH, Wt3, bufX, asrc, adst);
    aggregate_final_v4<<<N, 64, 0, stream>>>(bufX, asrc2, adst2, rp, col, b3, out);
}